// Round 7
// baseline (146.017 us; speedup 1.0000x reference)
//
#include <hip/hip_runtime.h>
#include <cstdint>
#include <cstddef>

#define S_TOT 2048
#define S0_   1023
#define S1_   1025
#define D_    256
#define D2_   512
#define DZ_   128
#define NB_   8
#define NT_   17            // 17 * 64 padded keys = 1088
#define KT16_ 68            // 17*4 16-key groups
#define SCALE_INV (1.0f/16.0f)
#define XPAD  264           // 256 + 8 bf16 pad
#define UPAD  520           // 512 + 8 bf16 pad

typedef __attribute__((ext_vector_type(8))) short short8v;
typedef __attribute__((ext_vector_type(4))) short short4v;
typedef __attribute__((ext_vector_type(4))) float f32x4;
typedef unsigned long long u64;

__device__ __forceinline__ short f2bf(float f){
  unsigned u = __float_as_uint(f);
  unsigned r = (u + 0x7FFFu + ((u >> 16) & 1u)) >> 16;
  return (short)r;
}
__device__ __forceinline__ float bf2f(short s){
  return __uint_as_float(((unsigned)(unsigned short)s) << 16);
}
__device__ __forceinline__ float silu_f(float x){ return x / (1.f + __expf(-x)); }

// A/B fragment load from a row-major row (verified layout, round 1):
// elems 0..3: k = kt*32 + khi + j ; elems 4..7: +16
__device__ __forceinline__ short8v load_afrag(const short* arow, int kt, int khi){
  short4v lo = *reinterpret_cast<const short4v*>(arow + kt*32 + khi);
  short4v hi = *reinterpret_cast<const short4v*>(arow + kt*32 + khi + 16);
  short8v r = {lo[0],lo[1],lo[2],lo[3],hi[0],hi[1],hi[2],hi[3]};
  return r;
}

// ------- k_prep: ALL weight packs + mask bitmask pack in ONE launch ---------
// blocks [0,304): weight packs (4 tiles/block); blocks [304,35086): maskpack
__global__ __launch_bounds__(256) void k_prep(
    const float* __restrict__ W_init, const float* __restrict__ W_U,
    const float* __restrict__ W_V,    const float* __restrict__ W_Z,
    const float* __restrict__ W_out,  const float* __restrict__ W_gate,
    short* __restrict__ WpI, short* __restrict__ WpU, short* __restrict__ WpV,
    short* __restrict__ WpZ, short* __restrict__ WpO, short* __restrict__ WpG,
    const unsigned char* __restrict__ amask, u64* __restrict__ maskb)
{
  const int blk = blockIdx.x;
  if (blk < 304){
    const float* W; short* dst; int K, N, base;
    if      (blk <  32){ W=W_init; dst=WpI; K=256; N=256; base=0;   }
    else if (blk <  96){ W=W_U;    dst=WpU; K=256; N=512; base=32;  }
    else if (blk < 160){ W=W_V;    dst=WpV; K=256; N=512; base=96;  }
    else if (blk < 176){ W=W_Z;    dst=WpZ; K=256; N=128; base=160; }
    else if (blk < 240){ W=W_out;  dst=WpO; K=512; N=256; base=176; }
    else               { W=W_gate; dst=WpG; K=512; N=256; base=240; }
    const int wv = threadIdx.x >> 6, lane = threadIdx.x & 63;
    const int KT = K >> 5;
    const int tile = (blk - base)*4 + wv;
    const int nt = tile / KT, kt = tile - nt*KT;
    const int n = nt*16 + (lane & 15);
    const int kbase = kt*32 + ((lane>>4)<<2);
    short8v v;
    #pragma unroll
    for (int j=0;j<8;++j){
      int k = kbase + (j&3) + ((j>>2)<<4);
      v[j] = f2bf(W[(size_t)k*N + n]);
    }
    *reinterpret_cast<short8v*>(dst + ((size_t)tile*64 + lane)*8) = v;
  } else {
    const int lane = threadIdx.x & 63;
    const int w = (blk - 304)*4 + (threadIdx.x >> 6);
    if (w >= NB_*S0_*NT_) return;
    int b = w / (S0_*NT_);
    int rem = w - b*(S0_*NT_);
    int q = rem / NT_;
    int t = rem - q*NT_;
    int key = t*64 + lane;
    unsigned char v = 0;
    if (key < S1_) v = amask[((size_t)(b*S_TOT + q))*S_TOT + S0_ + key];
    u64 bits = __ballot(v != 0);
    if (lane == 0) maskb[w] = bits;
  }
}

// ---------------- kernel 1a: x = LN(seq@W_init + b) -> bf16; tail rows->out -
__global__ __launch_bounds__(256) void k_x(
    const float* __restrict__ seq, const short* __restrict__ Wp,
    const float* __restrict__ b_init,
    const float* __restrict__ ln_g, const float* __restrict__ ln_b,
    short* __restrict__ xb, float* __restrict__ out)
{
  __shared__ short s_a[64*XPAD];
  const int tid = threadIdx.x, lane = tid & 63, wv = tid >> 6;
  const int R0 = blockIdx.x * 64;
  const int colb = lane & 15, khi = (lane>>4)<<2;

  for (int c = tid; c < 64*64; c += 256){
    int row = c >> 6, c4 = (c & 63) << 2;
    int g = R0 + row;
    float4 f = *reinterpret_cast<const float4*>(seq + (size_t)g*D_ + c4);
    short4v h = { f2bf(f.x), f2bf(f.y), f2bf(f.z), f2bf(f.w) };
    *reinterpret_cast<short4v*>(&s_a[row*XPAD + c4]) = h;
    if ((g & 2047) >= S0_)           // passthrough tail rows (was k_copy)
      *reinterpret_cast<float4*>(out + (size_t)g*D_ + c4) = f;
  }
  __syncthreads();

  f32x4 acc[16];
  #pragma unroll
  for (int nt=0;nt<16;++nt) acc[nt] = (f32x4){0.f,0.f,0.f,0.f};

  const short* arow = &s_a[(wv*16 + colb)*XPAD];
  #pragma unroll
  for (int kt=0; kt<8; ++kt){
    short8v a = load_afrag(arow, kt, khi);
    #pragma unroll
    for (int nt=0; nt<16; ++nt){
      short8v b = *reinterpret_cast<const short8v*>(Wp + ((size_t)(nt*8 + kt)*64 + lane)*8);
      acc[nt] = __builtin_amdgcn_mfma_f32_16x16x32_bf16(a, b, acc[nt], 0, 0, 0);
    }
  }

  float sum[4] = {0.f,0.f,0.f,0.f};
  #pragma unroll
  for (int nt=0; nt<16; ++nt){
    float bv = b_init[nt*16 + colb];
    #pragma unroll
    for (int r=0;r<4;++r){ acc[nt][r] += bv; sum[r] += acc[nt][r]; }
  }
  #pragma unroll
  for (int r=0;r<4;++r){
    #pragma unroll
    for (int m=1;m<16;m<<=1) sum[r] += __shfl_xor(sum[r], m, 64);
    sum[r] *= (1.f/256.f);
  }
  float var[4] = {0.f,0.f,0.f,0.f};
  #pragma unroll
  for (int nt=0; nt<16; ++nt)
    #pragma unroll
    for (int r=0;r<4;++r){ float d = acc[nt][r]-sum[r]; var[r] += d*d; }
  #pragma unroll
  for (int r=0;r<4;++r){
    #pragma unroll
    for (int m=1;m<16;m<<=1) var[r] += __shfl_xor(var[r], m, 64);
    var[r] = rsqrtf(var[r]*(1.f/256.f) + 1e-5f);
  }
  #pragma unroll
  for (int nt=0; nt<16; ++nt){
    int col = nt*16 + colb;
    float g = ln_g[col], bb = ln_b[col];
    #pragma unroll
    for (int r=0;r<4;++r){
      float xn = (acc[nt][r]-sum[r])*var[r]*g + bb;
      s_a[(wv*16 + ((lane>>4)<<2) + r)*XPAD + col] = f2bf(xn);
    }
  }
  __syncthreads();
  for (int c = tid; c < 64*32; c += 256){
    int row = c >> 5, c8 = (c & 31) << 3;
    *reinterpret_cast<short8v*>(xb + (size_t)(R0+row)*D_ + c8) =
        *reinterpret_cast<const short8v*>(&s_a[row*XPAD + c8]);
  }
}

// ---------------- kernel 1c: Z = silu(x@W_Z+b) -> bf16 row-major ------------
__global__ __launch_bounds__(256) void k_gemmZ(
    const short* __restrict__ xb, const short* __restrict__ Wp,
    const float* __restrict__ bias, short* __restrict__ Zb)
{
  __shared__ short s_a[64*XPAD];
  const int tid = threadIdx.x, lane = tid & 63, wv = tid >> 6;
  const int wy = wv >> 1, wx = wv & 1;
  const int R0 = blockIdx.x * 64;
  const int C0 = blockIdx.y * 64;
  const int colb = lane & 15, khi = (lane>>4)<<2;

  for (int c = tid; c < 64*32; c += 256){
    int r = c >> 5, c8 = (c & 31) << 3;
    size_t xrow = (size_t)(R0 + r);
    *reinterpret_cast<short8v*>(&s_a[r*XPAD + c8]) =
        *reinterpret_cast<const short8v*>(xb + xrow*D_ + c8);
  }
  __syncthreads();

  f32x4 acc[2][2];
  #pragma unroll
  for(int i=0;i<2;++i)
    #pragma unroll
    for(int j=0;j<2;++j) acc[i][j] = (f32x4){0.f,0.f,0.f,0.f};

  const short* ar0 = &s_a[(wy*32 + colb)*XPAD];
  const short* ar1 = ar0 + 16*XPAD;
  const int ntg = (C0 >> 4) + wx*2;
  #pragma unroll
  for (int kt=0; kt<8; ++kt){
    short8v a0 = load_afrag(ar0, kt, khi);
    short8v a1 = load_afrag(ar1, kt, khi);
    short8v b0 = *reinterpret_cast<const short8v*>(Wp + ((size_t)((ntg+0)*8 + kt)*64 + lane)*8);
    short8v b1 = *reinterpret_cast<const short8v*>(Wp + ((size_t)((ntg+1)*8 + kt)*64 + lane)*8);
    acc[0][0] = __builtin_amdgcn_mfma_f32_16x16x32_bf16(a0, b0, acc[0][0], 0,0,0);
    acc[0][1] = __builtin_amdgcn_mfma_f32_16x16x32_bf16(a0, b1, acc[0][1], 0,0,0);
    acc[1][0] = __builtin_amdgcn_mfma_f32_16x16x32_bf16(a1, b0, acc[1][0], 0,0,0);
    acc[1][1] = __builtin_amdgcn_mfma_f32_16x16x32_bf16(a1, b1, acc[1][1], 0,0,0);
  }
  #pragma unroll
  for (int sj=0; sj<2; ++sj){
    int col = C0 + wx*32 + sj*16 + colb;
    float bv = bias[col];
    #pragma unroll
    for (int si=0; si<2; ++si){
      #pragma unroll
      for (int r=0;r<4;++r){
        int orow = R0 + wy*32 + si*16 + ((lane>>4)<<2) + r;
        Zb[(size_t)orow*DZ_ + col] = f2bf(silu_f(acc[si][sj][r] + bv));
      }
    }
  }
}

// ------- kernel 1c2: pack Z key rows -> A-fragment order (for flash QK) -----
__global__ __launch_bounds__(256) void k_packZ(const short* __restrict__ Zb,
                                               short* __restrict__ ZkF){
  const int lane = threadIdx.x & 63;
  const int w = blockIdx.x*4 + (threadIdx.x >> 6);
  if (w >= NB_*KT16_*4) return;
  const int b = w / (KT16_*4);
  const int rem = w - b*(KT16_*4);
  const int kt16 = rem >> 2, kt = rem & 3;
  int key = kt16*16 + (lane & 15); if (key > 1024) key = 1024;
  const short* zr = Zb + ((size_t)(b*S_TOT + S0_ + key))*DZ_ + kt*32 + ((lane>>4)<<2);
  short4v lo = *reinterpret_cast<const short4v*>(zr);
  short4v hi = *reinterpret_cast<const short4v*>(zr + 16);
  short8v f = {lo[0],lo[1],lo[2],lo[3],hi[0],hi[1],hi[2],hi[3]};
  *reinterpret_cast<short8v*>(ZkF + ((size_t)w*64 + lane)*8) = f;
}

// ---------------- kernel 1d: V -> bf16 B-fragment order VtF -----------------
__global__ __launch_bounds__(256) void k_gemmV(
    const short* __restrict__ xb, const short* __restrict__ Wp,
    const float* __restrict__ bias, short* __restrict__ VtF)
{
  __shared__ short s_a[64*XPAD];
  __shared__ short s_t[64][72];
  const int tid = threadIdx.x, lane = tid & 63, wv = tid >> 6;
  const int wy = wv >> 1, wx = wv & 1;
  const int R0 = blockIdx.x * 64;     // key base within batch (tile t = R0/64)
  const int C0 = blockIdx.y * 64;     // v base
  const int b  = blockIdx.z;
  const int colb = lane & 15, khi = (lane>>4)<<2;

  for (int c = tid; c < 64*32; c += 256){
    int r = c >> 5, c8 = (c & 31) << 3;
    int k = R0 + r; if (k > 1024) k = 1024;
    size_t xrow = (size_t)b*S_TOT + S0_ + k;
    *reinterpret_cast<short8v*>(&s_a[r*XPAD + c8]) =
        *reinterpret_cast<const short8v*>(xb + xrow*D_ + c8);
  }
  __syncthreads();

  f32x4 acc[2][2];
  #pragma unroll
  for(int i=0;i<2;++i)
    #pragma unroll
    for(int j=0;j<2;++j) acc[i][j] = (f32x4){0.f,0.f,0.f,0.f};

  const short* ar0 = &s_a[(wy*32 + colb)*XPAD];
  const short* ar1 = ar0 + 16*XPAD;
  const int ntg = (C0 >> 4) + wx*2;
  #pragma unroll
  for (int kt=0; kt<8; ++kt){
    short8v a0 = load_afrag(ar0, kt, khi);
    short8v a1 = load_afrag(ar1, kt, khi);
    short8v b0 = *reinterpret_cast<const short8v*>(Wp + ((size_t)((ntg+0)*8 + kt)*64 + lane)*8);
    short8v b1 = *reinterpret_cast<const short8v*>(Wp + ((size_t)((ntg+1)*8 + kt)*64 + lane)*8);
    acc[0][0] = __builtin_amdgcn_mfma_f32_16x16x32_bf16(a0, b0, acc[0][0], 0,0,0);
    acc[0][1] = __builtin_amdgcn_mfma_f32_16x16x32_bf16(a0, b1, acc[0][1], 0,0,0);
    acc[1][0] = __builtin_amdgcn_mfma_f32_16x16x32_bf16(a1, b0, acc[1][0], 0,0,0);
    acc[1][1] = __builtin_amdgcn_mfma_f32_16x16x32_bf16(a1, b1, acc[1][1], 0,0,0);
  }
  // silu + transpose into LDS [v_local][key_local]
  #pragma unroll
  for (int sj=0; sj<2; ++sj){
    int cl = wx*32 + sj*16 + colb;
    float bv = bias[C0 + cl];
    #pragma unroll
    for (int si=0; si<2; ++si){
      #pragma unroll
      for (int r=0;r<4;++r){
        int rl = wy*32 + si*16 + ((lane>>4)<<2) + r;
        s_t[cl][rl] = f2bf(silu_f(acc[si][sj][r] + bv));
      }
    }
  }
  __syncthreads();
  // emit B-fragments (zero pad for key >= S1_)
  {
    const int vt_l = tid >> 6;           // 0..3: v-tile within C0
    const int vloc = vt_l*16 + (lane & 15);
    const int krow = (lane>>4)<<2;
    const int t = R0 >> 6;
    #pragma unroll
    for (int kt=0; kt<2; ++kt){
      short8v f;
      #pragma unroll
      for (int j=0;j<8;++j){
        int kl = kt*32 + krow + (j&3) + ((j>>2)<<4);
        short v = s_t[vloc][kl];
        if (R0 + kl >= S1_) v = 0;
        f[j] = v;
      }
      size_t o = (((size_t)b*32 + (C0>>4) + vt_l)*(2*NT_) + 2*t + kt)*64 + lane;
      *reinterpret_cast<short8v*>(VtF + o*8) = f;
    }
  }
}

// ------ kernel 2: fused flash attention + U-proj + out-proj + gating --------
// block = (batch b, q-tile of 16); wave wv owns v-slice wv*128..+127
// LDS union: attention-phase {s_qg, s_pl, s_ph} overlap epilogue {sUV, sO};
// sX/sR live in a disjoint region. 50.4 KB total -> 3 blocks/CU.
#define SMEM_BYTES 41984
__global__ __launch_bounds__(256,3) void k_flash(
    const short* __restrict__ Zb, const short* __restrict__ ZkF,
    const short* __restrict__ VtF, const u64* __restrict__ maskb,
    const short* __restrict__ xb,
    const short* __restrict__ WpU, const float* __restrict__ b_U,
    const short* __restrict__ Wpo, const float* __restrict__ b_out,
    const short* __restrict__ Wpg, const float* __restrict__ b_gate,
    const float* __restrict__ seq, float* __restrict__ out,
    const int* __restrict__ heights,
    const float* __restrict__ os_g, const float* __restrict__ os_b,
    const float* __restrict__ embH)
{
  __shared__ __align__(16) char smem[SMEM_BYTES];
  __shared__ float  s_qh[16][12];
  __shared__ float  s_qb[16];
  __shared__ int    s_hk[NT_*64];
  __shared__ u64    s_mb[16][NT_];
  __shared__ float  s_mx[2][4][16];
  __shared__ float  s_sm[2][4][16];

  // attention-phase views (dead before epilogue)
  short   (*s_qg)[132] = reinterpret_cast<short(*)[132]>(smem);          // [16][132]
  short8v (*s_pl)[64]  = reinterpret_cast<short8v(*)[64]>(smem + 4224);  // [8][64]
  short8v (*s_ph)[64]  = reinterpret_cast<short8v(*)[64]>(smem + 12416); // [8][64] ->20608
  // epilogue views (sUV/sO overlap the above; sX/sR disjoint, live whole kernel)
  short* sUV = reinterpret_cast<short*>(smem);            // 16*UPAD -> 16640 B
  short* sO  = reinterpret_cast<short*>(smem + 16640);    // 16*XPAD -> 8448 B
  short* sX  = reinterpret_cast<short*>(smem + 25088);    // 16*XPAD
  short* sR  = reinterpret_cast<short*>(smem + 33536);    // 16*XPAD -> 41984

  const int tid = threadIdx.x, lane = tid & 63, wv = tid >> 6;
  const int b  = blockIdx.x & 7;
  const int qt = blockIdx.x >> 3;
  const int q0 = qt * 16;

  // ---- stage x rows (bf16) and res rows (fp32 -> bf16)
  for (int c = tid; c < 16*32; c += 256){
    int r = c >> 5, c8 = (c & 31) << 3;
    int q = min(q0 + r, S0_-1);
    *reinterpret_cast<short8v*>(&sX[r*XPAD + c8]) =
        *reinterpret_cast<const short8v*>(xb + ((size_t)(b*S_TOT + q))*D_ + c8);
  }
  for (int c = tid; c < 16*64; c += 256){
    int r = c >> 6, c4 = (c & 63) << 2;
    int q = min(q0 + r, S0_-1);
    float4 f = *reinterpret_cast<const float4*>(seq + ((size_t)(b*S_TOT + q))*D_ + c4);
    short4v h = { f2bf(f.x), f2bf(f.y), f2bf(f.z), f2bf(f.w) };
    *reinterpret_cast<short4v*>(&sR[r*XPAD + c4]) = h;
  }

  // ---- Q prep: 16 threads per q-row, 8 dz each
  {
    int row = tid >> 4, part = tid & 15;
    int q = q0 + row; if (q > S0_-1) q = S0_-1;
    const short* zrow = Zb + ((size_t)(b*S_TOT + q))*DZ_ + part*8;
    float qb_acc = 0.f;
    float qh_acc[10];
    #pragma unroll
    for (int h=0;h<10;++h) qh_acc[h] = 0.f;
    #pragma unroll
    for (int e=0; e<8; ++e){
      int dz = part*8 + e;
      float z = bf2f(zrow[e]);
      float Q  = z*os_g[dz]      + os_b[dz];
      float Qp = z*os_g[DZ_+dz]  + os_b[DZ_+dz];
      s_qg[row][dz] = f2bf(Q * os_g[2*DZ_+dz]);
      qb_acc += Q * os_b[2*DZ_+dz];
      #pragma unroll
      for (int h=0;h<10;++h) qh_acc[h] += Qp * embH[h*DZ_ + dz];
    }
    #pragma unroll
    for (int m=1;m<16;m<<=1){
      qb_acc += __shfl_xor(qb_acc, m, 64);
      #pragma unroll
      for (int h=0;h<10;++h) qh_acc[h] += __shfl_xor(qh_acc[h], m, 64);
    }
    if (part == 0){
      s_qb[row] = qb_acc;
      #pragma unroll
      for (int h=0;h<10;++h) s_qh[row][h] = qh_acc[h];
    }
  }
  for (int k = tid; k < NT_*64; k += 256)
    s_hk[k] = (k < S1_) ? heights[b*S_TOT + S0_ + k] : 0;
  for (int idx = tid; idx < 16*NT_; idx += 256){
    int qq = idx / NT_, tt = idx - qq*NT_;
    int qr = q0 + qq; if (qr > S0_-1) qr = S0_-1;
    s_mb[qq][tt] = maskb[((size_t)(b*S0_ + qr))*NT_ + tt];
  }
  __syncthreads();

  const int qcol = lane & 15, khi = (lane>>4)<<2;
  int qme = q0 + qcol; if (qme > S0_-1) qme = S0_-1;
  const int hq = heights[b*S_TOT + qme];
  const float qb = s_qb[qcol];

  short8v qgf[4];
  #pragma unroll
  for (int kt=0; kt<4; ++kt) qgf[kt] = load_afrag(&s_qg[qcol][0], kt, khi);

  float mcol = -1e30f;
  float mrow[4] = {-1e30f,-1e30f,-1e30f,-1e30f};
  float lrow[4] = {0.f,0.f,0.f,0.f};
  f32x4 O[8];
  #pragma unroll
  for (int vt=0; vt<8; ++vt) O[vt] = (f32x4){0.f,0.f,0.f,0.f};

  int buf = 0;
  for (int it=0; it<5; ++it){
    const int t = it*4 + wv;
    const bool tvalid = (t < NT_);
    f32x4 sc[4];
    float tm = -1e30f;
    // ---- phase A: own tile's QK^T + bias + mask
    if (tvalid){
      #pragma unroll
      for (int st=0; st<4; ++st){
        f32x4 c = (f32x4){0.f,0.f,0.f,0.f};
        #pragma unroll
        for (int kt=0; kt<4; ++kt){
          short8v a = *reinterpret_cast<const short8v*>(
              ZkF + (((size_t)(b*KT16_ + t*4 + st)*4 + kt)*64 + lane)*8);
          c = __builtin_amdgcn_mfma_f32_16x16x32_bf16(a, qgf[kt], c, 0,0,0);
        }
        sc[st] = c;
      }
      u64 mb = s_mb[qcol][t];
      #pragma unroll
      for (int st=0; st<4; ++st){
        int4 hk4 = *reinterpret_cast<const int4*>(&s_hk[t*64 + st*16 + khi]);
        #pragma unroll
        for (int r=0;r<4;++r){
          int hk = (&hk4.x)[r];
          int idx = min(max(hk - hq, 1), 10) - 1;
          float v = (sc[st][r] + qb + s_qh[qcol][idx]) * SCALE_INV;
          int kl = st*16 + khi + r;
          v = ((mb >> kl) & 1ull) ? v : -9999.f;
          sc[st][r] = v;
          tm = fmaxf(tm, v);
        }
      }
      tm = fmaxf(tm, __shfl_xor(tm, 16, 64));
      tm = fmaxf(tm, __shfl_xor(tm, 32, 64));
    }
    if (lane < 16) s_mx[buf][wv][lane] = tm;
    __syncthreads();

    // ---- phase B: combined max, defer-max rescale, exp, pack P
    float cmc = fmaxf(fmaxf(s_mx[buf][0][qcol], s_mx[buf][1][qcol]),
                      fmaxf(s_mx[buf][2][qcol], s_mx[buf][3][qcol]));
    if (__any(cmc > mcol + 8.f)){
      mcol = fmaxf(mcol, cmc);
      #pragma unroll
      for (int r=0;r<4;++r){
        int qr = khi + r;
        float cmr = fmaxf(fmaxf(s_mx[buf][0][qr], s_mx[buf][1][qr]),
                          fmaxf(s_mx[buf][2][qr], s_mx[buf][3][qr]));
        float mn = fmaxf(mrow[r], cmr);
        float s = __expf(mrow[r] - mn);
        lrow[r] *= s; mrow[r] = mn;
        #pragma unroll
        for (int vt=0; vt<8; ++vt) O[vt][r] *= s;
      }
    }
    float ls = 0.f;
    if (tvalid){
      #pragma unroll
      for (int st=0; st<4; ++st)
        #pragma unroll
        for (int r=0;r<4;++r){
          float p = __expf(sc[st][r] - mcol);
          ls += p; sc[st][r] = p;
        }
    }
    ls += __shfl_xor(ls, 16, 64);
    ls += __shfl_xor(ls, 32, 64);
    if (lane < 16) s_sm[buf][wv][lane] = ls;
    if (tvalid){
      short8v pa0, pa1;
      #pragma unroll
      for (int j=0;j<8;++j){
        pa0[j] = f2bf(sc[(j>>2)][j&3]);
        pa1[j] = f2bf(sc[2 + (j>>2)][j&3]);
      }
      s_pl[buf*4 + wv][lane] = pa0;
      s_ph[buf*4 + wv][lane] = pa1;
    }
    __syncthreads();

    // ---- phase C: accumulate l; PV over the 4 tiles for own v-slice
    #pragma unroll
    for (int r=0;r<4;++r){
      int qr = khi + r;
      lrow[r] += s_sm[buf][0][qr] + s_sm[buf][1][qr] + s_sm[buf][2][qr] + s_sm[buf][3][qr];
    }
    #pragma unroll
    for (int tw=0; tw<4; ++tw){
      int tl = it*4 + tw;
      if (tl >= NT_) break;
      short8v pa0 = s_pl[buf*4 + tw][lane];
      short8v pa1 = s_ph[buf*4 + tw][lane];
      #pragma unroll
      for (int vt=0; vt<8; ++vt){
        size_t vb = ((size_t)b*32 + wv*8 + vt)*(2*NT_) + 2*tl;
        short8v b0 = *reinterpret_cast<const short8v*>(VtF + (vb*64 + lane)*8);
        short8v b1 = *reinterpret_cast<const short8v*>(VtF + ((vb+1)*64 + lane)*8);
        O[vt] = __builtin_amdgcn_mfma_f32_16x16x32_bf16(pa0, b0, O[vt], 0,0,0);
        O[vt] = __builtin_amdgcn_mfma_f32_16x16x32_bf16(pa1, b1, O[vt], 0,0,0);
      }
    }
    buf ^= 1;
  }
  __syncthreads();   // protect s_pl/s_ph (unioned with sUV/sO) before epilogue

  // ---- U = silu(x @ W_U + b) for own v-slice; uv = U * O / l -> sUV (bf16)
  f32x4 accu[8];
  #pragma unroll
  for (int vt=0; vt<8; ++vt) accu[vt] = (f32x4){0.f,0.f,0.f,0.f};
  {
    const short* xrow = &sX[qcol*XPAD];
    #pragma unroll
    for (int kt=0; kt<8; ++kt){
      short8v a = load_afrag(xrow, kt, khi);
      #pragma unroll
      for (int vt=0; vt<8; ++vt){
        int nt = wv*8 + vt;
        short8v bw = *reinterpret_cast<const short8v*>(WpU + ((size_t)(nt*8 + kt)*64 + lane)*8);
        accu[vt] = __builtin_amdgcn_mfma_f32_16x16x32_bf16(a, bw, accu[vt], 0,0,0);
      }
    }
  }
  float inv[4];
  #pragma unroll
  for (int r=0;r<4;++r) inv[r] = 1.f / lrow[r];
  #pragma unroll
  for (int vt=0; vt<8; ++vt){
    int v = wv*128 + vt*16 + qcol;
    float bu = b_U[v];
    #pragma unroll
    for (int r=0;r<4;++r){
      float u = silu_f(accu[vt][r] + bu);
      sUV[(khi + r)*UPAD + v] = f2bf(u * O[vt][r] * inv[r]);
    }
  }
  __syncthreads();

  // ---- out-proj: o = UV @ W_out + b (each wave: 4 n-tiles, K=512)
  f32x4 acc_o[4];
  #pragma unroll
  for (int j=0;j<4;++j) acc_o[j] = (f32x4){0.f,0.f,0.f,0.f};
  {
    const short* arow = &sUV[qcol*UPAD];
    #pragma unroll
    for (int kt=0; kt<16; ++kt){
      short8v a = load_afrag(arow, kt, khi);
      #pragma unroll
      for (int j=0;j<4;++j){
        int nt = wv*4 + j;
        short8v bw = *reinterpret_cast<const short8v*>(Wpo + ((size_t)(nt*16 + kt)*64 + lane)*8);
        acc_o[j] = __builtin_amdgcn_mfma_f32_16x16x32_bf16(a, bw, acc_o[j], 0,0,0);
      }
    }
  }
  #pragma unroll
  for (int j=0;j<4;++j){
    int col = (wv*4+j)*16 + qcol;
    float bv = b_out[col];
    #pragma unroll
    for (int r=0;r<4;++r){
      acc_o[j][r] += bv;
      sO[(khi + r)*XPAD + col] = f2bf(acc_o[j][r]);
    }
  }
  __syncthreads();

  // ---- gate = sigmoid([o, res] @ W_gate + b); final mix + write
  f32x4 acc_g[4];
  #pragma unroll
  for (int j=0;j<4;++j) acc_g[j] = (f32x4){0.f,0.f,0.f,0.f};
  {
    const short* orow_p = &sO[qcol*XPAD];
    const short* rrow_p = &sR[qcol*XPAD];
    #pragma unroll
    for (int kt=0; kt<8; ++kt){
      short8v a = load_afrag(orow_p, kt, khi);
      #pragma unroll
      for (int j=0;j<4;++j){
        int nt = wv*4 + j;
        short8v bw = *reinterpret_cast<const short8v*>(Wpg + ((size_t)(nt*16 + kt)*64 + lane)*8);
        acc_g[j] = __builtin_amdgcn_mfma_f32_16x16x32_bf16(a, bw, acc_g[j], 0,0,0);
      }
    }
    #pragma unroll
    for (int kt=0; kt<8; ++kt){
      short8v a = load_afrag(rrow_p, kt, khi);
      #pragma unroll
      for (int j=0;j<4;++j){
        int nt = wv*4 + j;
        short8v bw = *reinterpret_cast<const short8v*>(Wpg + ((size_t)(nt*16 + 8 + kt)*64 + lane)*8);
        acc_g[j] = __builtin_amdgcn_mfma_f32_16x16x32_bf16(a, bw, acc_g[j], 0,0,0);
      }
    }
  }
  #pragma unroll
  for (int j=0;j<4;++j){
    int col = (wv*4+j)*16 + qcol;
    float bg = b_gate[col];
    #pragma unroll
    for (int r=0;r<4;++r){
      int q = q0 + khi + r;
      if (q < S0_){
        float res = seq[((size_t)(b*S_TOT + q))*D_ + col];
        float g = 1.f/(1.f + __expf(-(acc_g[j][r] + bg)));
        out[((size_t)(b*S_TOT + q))*D_ + col] = g*acc_o[j][r] + (1.f-g)*res;
      }
    }
  }
}

extern "C" void kernel_launch(void* const* d_in, const int* in_sizes, int n_in,
                              void* d_out, int out_size, void* d_ws, size_t ws_size,
                              hipStream_t stream)
{
  const float* seq    = (const float*)d_in[0];
  const unsigned char* amask = (const unsigned char*)d_in[1];
  const int*   heights= (const int*)d_in[2];
  const float* W_init = (const float*)d_in[3];
  const float* b_init = (const float*)d_in[4];
  const float* ln_g   = (const float*)d_in[5];
  const float* ln_b   = (const float*)d_in[6];
  const float* W_U    = (const float*)d_in[7];
  const float* b_U    = (const float*)d_in[8];
  const float* W_V    = (const float*)d_in[9];
  const float* b_V    = (const float*)d_in[10];
  const float* W_Z    = (const float*)d_in[11];
  const float* b_Z    = (const float*)d_in[12];
  const float* os_g   = (const float*)d_in[13];
  const float* os_b   = (const float*)d_in[14];
  const float* embH   = (const float*)d_in[15];
  const float* W_out  = (const float*)d_in[16];
  const float* b_out  = (const float*)d_in[17];
  const float* W_gate = (const float*)d_in[18];
  const float* b_gate = (const float*)d_in[19];
  float* out = (float*)d_out;

  char* w = (char*)d_ws;
  short* Zb  = (short*)w;                w += (size_t)16512*128*2;         // bf16 Z row-major
  short* VtF = (short*)w;                w += (size_t)8*32*(2*NT_)*64*8*2; // V B-frags
  short* ZkF = (short*)w;                w += (size_t)NB_*KT16_*4*64*8*2;  // Z-key A-frags
  short* xb  = (short*)w;                w += (size_t)16384*256*2;
  u64*  maskb = (u64*)w;                 w += (size_t)NB_*S0_*NT_*8;
  short* WpI = (short*)w;                w += (size_t)65536*2;
  short* WpU = (short*)w;                w += (size_t)131072*2;
  short* WpV = (short*)w;                w += (size_t)131072*2;
  short* WpZ = (short*)w;                w += (size_t)32768*2;
  short* WpO = (short*)w;                w += (size_t)131072*2;
  short* WpG = (short*)w;                w += (size_t)131072*2;

  hipLaunchKernelGGL(k_prep, dim3(304 + (NB_*S0_*NT_ + 3)/4), dim3(256), 0, stream,
      W_init, W_U, W_V, W_Z, W_out, W_gate,
      WpI, WpU, WpV, WpZ, WpO, WpG, amask, maskb);

  hipLaunchKernelGGL(k_x, dim3(256), dim3(256), 0, stream,
      seq, WpI, b_init, ln_g, ln_b, xb, out);

  hipLaunchKernelGGL(k_gemmZ, dim3(256, 2), dim3(256), 0, stream,
      xb, WpZ, b_Z, Zb);
  hipLaunchKernelGGL(k_packZ, dim3((NB_*KT16_*4 + 3)/4), dim3(256), 0, stream, Zb, ZkF);
  hipLaunchKernelGGL(k_gemmV, dim3(17, 8, 8), dim3(256), 0, stream,
      xb, WpV, b_V, VtF);

  hipLaunchKernelGGL(k_flash, dim3(512), dim3(256), 0, stream,
      Zb, ZkF, VtF, maskb, xb, WpU, b_U, WpO, b_out, WpG, b_gate,
      seq, out, heights, os_g, os_b, embH);
}

// Round 8
// 115.862 us; speedup vs baseline: 1.2603x; 1.2603x over previous
//
#include <hip/hip_runtime.h>
#include <cstdint>
#include <cstddef>

#define S_TOT 2048
#define S0_   1023
#define S1_   1025
#define D_    256
#define D2_   512
#define DZ_   128
#define NB_   8
#define NT_   17            // 17 * 64 padded keys = 1088
#define KT16_ 68            // 17*4 16-key groups
#define SCALE_INV (1.0f/16.0f)
#define XPAD  264           // 256 + 8 bf16 pad
#define UPAD  520           // 512 + 8 bf16 pad

typedef __attribute__((ext_vector_type(8))) short short8v;
typedef __attribute__((ext_vector_type(4))) short short4v;
typedef __attribute__((ext_vector_type(4))) float f32x4;
typedef unsigned long long u64;

__device__ __forceinline__ short f2bf(float f){
  unsigned u = __float_as_uint(f);
  unsigned r = (u + 0x7FFFu + ((u >> 16) & 1u)) >> 16;
  return (short)r;
}
__device__ __forceinline__ float bf2f(short s){
  return __uint_as_float(((unsigned)(unsigned short)s) << 16);
}
__device__ __forceinline__ float silu_f(float x){ return x / (1.f + __expf(-x)); }

// A/B fragment load from a row-major row (verified layout, round 1):
// elems 0..3: k = kt*32 + khi + j ; elems 4..7: +16
__device__ __forceinline__ short8v load_afrag(const short* arow, int kt, int khi){
  short4v lo = *reinterpret_cast<const short4v*>(arow + kt*32 + khi);
  short4v hi = *reinterpret_cast<const short4v*>(arow + kt*32 + khi + 16);
  short8v r = {lo[0],lo[1],lo[2],lo[3],hi[0],hi[1],hi[2],hi[3]};
  return r;
}

// ------- k_prep: ALL weight packs + mask bitmask pack in ONE launch ---------
__global__ __launch_bounds__(256) void k_prep(
    const float* __restrict__ W_init, const float* __restrict__ W_U,
    const float* __restrict__ W_V,    const float* __restrict__ W_Z,
    const float* __restrict__ W_out,  const float* __restrict__ W_gate,
    short* __restrict__ WpI, short* __restrict__ WpU, short* __restrict__ WpV,
    short* __restrict__ WpZ, short* __restrict__ WpO, short* __restrict__ WpG,
    const unsigned char* __restrict__ amask, u64* __restrict__ maskb)
{
  const int blk = blockIdx.x;
  if (blk < 304){
    const float* W; short* dst; int K, N, base;
    if      (blk <  32){ W=W_init; dst=WpI; K=256; N=256; base=0;   }
    else if (blk <  96){ W=W_U;    dst=WpU; K=256; N=512; base=32;  }
    else if (blk < 160){ W=W_V;    dst=WpV; K=256; N=512; base=96;  }
    else if (blk < 176){ W=W_Z;    dst=WpZ; K=256; N=128; base=160; }
    else if (blk < 240){ W=W_out;  dst=WpO; K=512; N=256; base=176; }
    else               { W=W_gate; dst=WpG; K=512; N=256; base=240; }
    const int wv = threadIdx.x >> 6, lane = threadIdx.x & 63;
    const int KT = K >> 5;
    const int tile = (blk - base)*4 + wv;
    const int nt = tile / KT, kt = tile - nt*KT;
    const int n = nt*16 + (lane & 15);
    const int kbase = kt*32 + ((lane>>4)<<2);
    short8v v;
    #pragma unroll
    for (int j=0;j<8;++j){
      int k = kbase + (j&3) + ((j>>2)<<4);
      v[j] = f2bf(W[(size_t)k*N + n]);
    }
    *reinterpret_cast<short8v*>(dst + ((size_t)tile*64 + lane)*8) = v;
  } else {
    const int lane = threadIdx.x & 63;
    const int w = (blk - 304)*4 + (threadIdx.x >> 6);
    if (w >= NB_*S0_*NT_) return;
    int b = w / (S0_*NT_);
    int rem = w - b*(S0_*NT_);
    int q = rem / NT_;
    int t = rem - q*NT_;
    int key = t*64 + lane;
    unsigned char v = 0;
    if (key < S1_) v = amask[((size_t)(b*S_TOT + q))*S_TOT + S0_ + key];
    u64 bits = __ballot(v != 0);
    if (lane == 0) maskb[w] = bits;
  }
}

// ---------------- kernel 1a: x = LN(seq@W_init + b) -> bf16; tail rows->out -
__global__ __launch_bounds__(256) void k_x(
    const float* __restrict__ seq, const short* __restrict__ Wp,
    const float* __restrict__ b_init,
    const float* __restrict__ ln_g, const float* __restrict__ ln_b,
    short* __restrict__ xb, float* __restrict__ out)
{
  __shared__ short s_a[64*XPAD];
  const int tid = threadIdx.x, lane = tid & 63, wv = tid >> 6;
  const int R0 = blockIdx.x * 64;
  const int colb = lane & 15, khi = (lane>>4)<<2;

  for (int c = tid; c < 64*64; c += 256){
    int row = c >> 6, c4 = (c & 63) << 2;
    int g = R0 + row;
    float4 f = *reinterpret_cast<const float4*>(seq + (size_t)g*D_ + c4);
    short4v h = { f2bf(f.x), f2bf(f.y), f2bf(f.z), f2bf(f.w) };
    *reinterpret_cast<short4v*>(&s_a[row*XPAD + c4]) = h;
    if ((g & 2047) >= S0_)           // passthrough tail rows
      *reinterpret_cast<float4*>(out + (size_t)g*D_ + c4) = f;
  }
  __syncthreads();

  f32x4 acc[16];
  #pragma unroll
  for (int nt=0;nt<16;++nt) acc[nt] = (f32x4){0.f,0.f,0.f,0.f};

  const short* arow = &s_a[(wv*16 + colb)*XPAD];
  #pragma unroll
  for (int kt=0; kt<8; ++kt){
    short8v a = load_afrag(arow, kt, khi);
    #pragma unroll
    for (int nt=0; nt<16; ++nt){
      short8v b = *reinterpret_cast<const short8v*>(Wp + ((size_t)(nt*8 + kt)*64 + lane)*8);
      acc[nt] = __builtin_amdgcn_mfma_f32_16x16x32_bf16(a, b, acc[nt], 0, 0, 0);
    }
  }

  float sum[4] = {0.f,0.f,0.f,0.f};
  #pragma unroll
  for (int nt=0; nt<16; ++nt){
    float bv = b_init[nt*16 + colb];
    #pragma unroll
    for (int r=0;r<4;++r){ acc[nt][r] += bv; sum[r] += acc[nt][r]; }
  }
  #pragma unroll
  for (int r=0;r<4;++r){
    #pragma unroll
    for (int m=1;m<16;m<<=1) sum[r] += __shfl_xor(sum[r], m, 64);
    sum[r] *= (1.f/256.f);
  }
  float var[4] = {0.f,0.f,0.f,0.f};
  #pragma unroll
  for (int nt=0; nt<16; ++nt)
    #pragma unroll
    for (int r=0;r<4;++r){ float d = acc[nt][r]-sum[r]; var[r] += d*d; }
  #pragma unroll
  for (int r=0;r<4;++r){
    #pragma unroll
    for (int m=1;m<16;m<<=1) var[r] += __shfl_xor(var[r], m, 64);
    var[r] = rsqrtf(var[r]*(1.f/256.f) + 1e-5f);
  }
  #pragma unroll
  for (int nt=0; nt<16; ++nt){
    int col = nt*16 + colb;
    float g = ln_g[col], bb = ln_b[col];
    #pragma unroll
    for (int r=0;r<4;++r){
      float xn = (acc[nt][r]-sum[r])*var[r]*g + bb;
      s_a[(wv*16 + ((lane>>4)<<2) + r)*XPAD + col] = f2bf(xn);
    }
  }
  __syncthreads();
  for (int c = tid; c < 64*32; c += 256){
    int row = c >> 5, c8 = (c & 31) << 3;
    *reinterpret_cast<short8v*>(xb + (size_t)(R0+row)*D_ + c8) =
        *reinterpret_cast<const short8v*>(&s_a[row*XPAD + c8]);
  }
}

// ---------------- kernel 1c: Z = silu(x@W_Z+b) -> bf16 row-major ------------
__global__ __launch_bounds__(256) void k_gemmZ(
    const short* __restrict__ xb, const short* __restrict__ Wp,
    const float* __restrict__ bias, short* __restrict__ Zb)
{
  __shared__ short s_a[64*XPAD];
  const int tid = threadIdx.x, lane = tid & 63, wv = tid >> 6;
  const int wy = wv >> 1, wx = wv & 1;
  const int R0 = blockIdx.x * 64;
  const int C0 = blockIdx.y * 64;
  const int colb = lane & 15, khi = (lane>>4)<<2;

  for (int c = tid; c < 64*32; c += 256){
    int r = c >> 5, c8 = (c & 31) << 3;
    size_t xrow = (size_t)(R0 + r);
    *reinterpret_cast<short8v*>(&s_a[r*XPAD + c8]) =
        *reinterpret_cast<const short8v*>(xb + xrow*D_ + c8);
  }
  __syncthreads();

  f32x4 acc[2][2];
  #pragma unroll
  for(int i=0;i<2;++i)
    #pragma unroll
    for(int j=0;j<2;++j) acc[i][j] = (f32x4){0.f,0.f,0.f,0.f};

  const short* ar0 = &s_a[(wy*32 + colb)*XPAD];
  const short* ar1 = ar0 + 16*XPAD;
  const int ntg = (C0 >> 4) + wx*2;
  #pragma unroll
  for (int kt=0; kt<8; ++kt){
    short8v a0 = load_afrag(ar0, kt, khi);
    short8v a1 = load_afrag(ar1, kt, khi);
    short8v b0 = *reinterpret_cast<const short8v*>(Wp + ((size_t)((ntg+0)*8 + kt)*64 + lane)*8);
    short8v b1 = *reinterpret_cast<const short8v*>(Wp + ((size_t)((ntg+1)*8 + kt)*64 + lane)*8);
    acc[0][0] = __builtin_amdgcn_mfma_f32_16x16x32_bf16(a0, b0, acc[0][0], 0,0,0);
    acc[0][1] = __builtin_amdgcn_mfma_f32_16x16x32_bf16(a0, b1, acc[0][1], 0,0,0);
    acc[1][0] = __builtin_amdgcn_mfma_f32_16x16x32_bf16(a1, b0, acc[1][0], 0,0,0);
    acc[1][1] = __builtin_amdgcn_mfma_f32_16x16x32_bf16(a1, b1, acc[1][1], 0,0,0);
  }
  #pragma unroll
  for (int sj=0; sj<2; ++sj){
    int col = C0 + wx*32 + sj*16 + colb;
    float bv = bias[col];
    #pragma unroll
    for (int si=0; si<2; ++si){
      #pragma unroll
      for (int r=0;r<4;++r){
        int orow = R0 + wy*32 + si*16 + ((lane>>4)<<2) + r;
        Zb[(size_t)orow*DZ_ + col] = f2bf(silu_f(acc[si][sj][r] + bv));
      }
    }
  }
}

// ------- kernel 1c2: pack Z key rows -> A-fragment order (for flash QK) -----
__global__ __launch_bounds__(256) void k_packZ(const short* __restrict__ Zb,
                                               short* __restrict__ ZkF){
  const int lane = threadIdx.x & 63;
  const int w = blockIdx.x*4 + (threadIdx.x >> 6);
  if (w >= NB_*KT16_*4) return;
  const int b = w / (KT16_*4);
  const int rem = w - b*(KT16_*4);
  const int kt16 = rem >> 2, kt = rem & 3;
  int key = kt16*16 + (lane & 15); if (key > 1024) key = 1024;
  const short* zr = Zb + ((size_t)(b*S_TOT + S0_ + key))*DZ_ + kt*32 + ((lane>>4)<<2);
  short4v lo = *reinterpret_cast<const short4v*>(zr);
  short4v hi = *reinterpret_cast<const short4v*>(zr + 16);
  short8v f = {lo[0],lo[1],lo[2],lo[3],hi[0],hi[1],hi[2],hi[3]};
  *reinterpret_cast<short8v*>(ZkF + ((size_t)w*64 + lane)*8) = f;
}

// ---------------- kernel 1d: V -> bf16 B-fragment order VtF -----------------
__global__ __launch_bounds__(256) void k_gemmV(
    const short* __restrict__ xb, const short* __restrict__ Wp,
    const float* __restrict__ bias, short* __restrict__ VtF)
{
  __shared__ short s_a[64*XPAD];
  __shared__ short s_t[64][72];
  const int tid = threadIdx.x, lane = tid & 63, wv = tid >> 6;
  const int wy = wv >> 1, wx = wv & 1;
  const int R0 = blockIdx.x * 64;     // key base within batch (tile t = R0/64)
  const int C0 = blockIdx.y * 64;     // v base
  const int b  = blockIdx.z;
  const int colb = lane & 15, khi = (lane>>4)<<2;

  for (int c = tid; c < 64*32; c += 256){
    int r = c >> 5, c8 = (c & 31) << 3;
    int k = R0 + r; if (k > 1024) k = 1024;
    size_t xrow = (size_t)b*S_TOT + S0_ + k;
    *reinterpret_cast<short8v*>(&s_a[r*XPAD + c8]) =
        *reinterpret_cast<const short8v*>(xb + xrow*D_ + c8);
  }
  __syncthreads();

  f32x4 acc[2][2];
  #pragma unroll
  for(int i=0;i<2;++i)
    #pragma unroll
    for(int j=0;j<2;++j) acc[i][j] = (f32x4){0.f,0.f,0.f,0.f};

  const short* ar0 = &s_a[(wy*32 + colb)*XPAD];
  const short* ar1 = ar0 + 16*XPAD;
  const int ntg = (C0 >> 4) + wx*2;
  #pragma unroll
  for (int kt=0; kt<8; ++kt){
    short8v a0 = load_afrag(ar0, kt, khi);
    short8v a1 = load_afrag(ar1, kt, khi);
    short8v b0 = *reinterpret_cast<const short8v*>(Wp + ((size_t)((ntg+0)*8 + kt)*64 + lane)*8);
    short8v b1 = *reinterpret_cast<const short8v*>(Wp + ((size_t)((ntg+1)*8 + kt)*64 + lane)*8);
    acc[0][0] = __builtin_amdgcn_mfma_f32_16x16x32_bf16(a0, b0, acc[0][0], 0,0,0);
    acc[0][1] = __builtin_amdgcn_mfma_f32_16x16x32_bf16(a0, b1, acc[0][1], 0,0,0);
    acc[1][0] = __builtin_amdgcn_mfma_f32_16x16x32_bf16(a1, b0, acc[1][0], 0,0,0);
    acc[1][1] = __builtin_amdgcn_mfma_f32_16x16x32_bf16(a1, b1, acc[1][1], 0,0,0);
  }
  // silu + transpose into LDS [v_local][key_local]
  #pragma unroll
  for (int sj=0; sj<2; ++sj){
    int cl = wx*32 + sj*16 + colb;
    float bv = bias[C0 + cl];
    #pragma unroll
    for (int si=0; si<2; ++si){
      #pragma unroll
      for (int r=0;r<4;++r){
        int rl = wy*32 + si*16 + ((lane>>4)<<2) + r;
        s_t[cl][rl] = f2bf(silu_f(acc[si][sj][r] + bv));
      }
    }
  }
  __syncthreads();
  // emit B-fragments (zero pad for key >= S1_)
  {
    const int vt_l = tid >> 6;           // 0..3: v-tile within C0
    const int vloc = vt_l*16 + (lane & 15);
    const int krow = (lane>>4)<<2;
    const int t = R0 >> 6;
    #pragma unroll
    for (int kt=0; kt<2; ++kt){
      short8v f;
      #pragma unroll
      for (int j=0;j<8;++j){
        int kl = kt*32 + krow + (j&3) + ((j>>2)<<4);
        short v = s_t[vloc][kl];
        if (R0 + kl >= S1_) v = 0;
        f[j] = v;
      }
      size_t o = (((size_t)b*32 + (C0>>4) + vt_l)*(2*NT_) + 2*t + kt)*64 + lane;
      *reinterpret_cast<short8v*>(VtF + o*8) = f;
    }
  }
}

// ------ kernel 2: fused flash attention + U-proj + out-proj + gating --------
// block = (batch b, q-tile of 16); wave wv owns v-slice wv*128..+127
// 3-phase EXACT softmax: (1) all QK tiles + per-wave max, (2) global max +
// exp + pack ALL 17 P-tiles to LDS, (3) one uninterrupted PV stream.
// LDS union: {s_qg | s_pl+s_ph | sUV+sO} share one region; sX/sR disjoint.
#define SMEM_BYTES 51712
__global__ __launch_bounds__(256,2) void k_flash(
    const short* __restrict__ Zb, const short* __restrict__ ZkF,
    const short* __restrict__ VtF, const u64* __restrict__ maskb,
    const short* __restrict__ xb,
    const short* __restrict__ WpU, const float* __restrict__ b_U,
    const short* __restrict__ Wpo, const float* __restrict__ b_out,
    const short* __restrict__ Wpg, const float* __restrict__ b_gate,
    const float* __restrict__ seq, float* __restrict__ out,
    const int* __restrict__ heights,
    const float* __restrict__ os_g, const float* __restrict__ os_b,
    const float* __restrict__ embH)
{
  __shared__ __align__(16) char smem[SMEM_BYTES];
  __shared__ float  s_qh[16][12];
  __shared__ float  s_qb[16];
  __shared__ int    s_hk[NT_*64];
  __shared__ u64    s_mb[16][NT_];
  __shared__ float  s_mx[4][16];
  __shared__ float  s_sm[4][16];

  // P buffers (phases 2-3); s_qg overlays them (dead before P writes)
  short8v (*s_pl)[64] = reinterpret_cast<short8v(*)[64]>(smem);           // [17][64] 17408 B
  short8v (*s_ph)[64] = reinterpret_cast<short8v(*)[64]>(smem + 17408);   // [17][64] ->34816
  short   (*s_qg)[132] = reinterpret_cast<short(*)[132]>(smem);           // [16][132] 4224 B
  // epilogue views (overlay P; born after post-PV barrier)
  short* sUV = reinterpret_cast<short*>(smem);            // 16*UPAD -> 16640 B
  short* sO  = reinterpret_cast<short*>(smem + 16640);    // 16*XPAD -> 8448 B
  // disjoint, live whole kernel
  short* sX  = reinterpret_cast<short*>(smem + 34816);    // 16*XPAD
  short* sR  = reinterpret_cast<short*>(smem + 43264);    // 16*XPAD -> 51712

  const int tid = threadIdx.x, lane = tid & 63, wv = tid >> 6;
  const int b  = blockIdx.x & 7;
  const int qt = blockIdx.x >> 3;
  const int q0 = qt * 16;

  // ---- stage x rows (bf16) and res rows (fp32 -> bf16)
  for (int c = tid; c < 16*32; c += 256){
    int r = c >> 5, c8 = (c & 31) << 3;
    int q = min(q0 + r, S0_-1);
    *reinterpret_cast<short8v*>(&sX[r*XPAD + c8]) =
        *reinterpret_cast<const short8v*>(xb + ((size_t)(b*S_TOT + q))*D_ + c8);
  }
  for (int c = tid; c < 16*64; c += 256){
    int r = c >> 6, c4 = (c & 63) << 2;
    int q = min(q0 + r, S0_-1);
    float4 f = *reinterpret_cast<const float4*>(seq + ((size_t)(b*S_TOT + q))*D_ + c4);
    short4v h = { f2bf(f.x), f2bf(f.y), f2bf(f.z), f2bf(f.w) };
    *reinterpret_cast<short4v*>(&sR[r*XPAD + c4]) = h;
  }

  // ---- Q prep: 16 threads per q-row, 8 dz each
  {
    int row = tid >> 4, part = tid & 15;
    int q = q0 + row; if (q > S0_-1) q = S0_-1;
    const short* zrow = Zb + ((size_t)(b*S_TOT + q))*DZ_ + part*8;
    float qb_acc = 0.f;
    float qh_acc[10];
    #pragma unroll
    for (int h=0;h<10;++h) qh_acc[h] = 0.f;
    #pragma unroll
    for (int e=0; e<8; ++e){
      int dz = part*8 + e;
      float z = bf2f(zrow[e]);
      float Q  = z*os_g[dz]      + os_b[dz];
      float Qp = z*os_g[DZ_+dz]  + os_b[DZ_+dz];
      s_qg[row][dz] = f2bf(Q * os_g[2*DZ_+dz]);
      qb_acc += Q * os_b[2*DZ_+dz];
      #pragma unroll
      for (int h=0;h<10;++h) qh_acc[h] += Qp * embH[h*DZ_ + dz];
    }
    #pragma unroll
    for (int m=1;m<16;m<<=1){
      qb_acc += __shfl_xor(qb_acc, m, 64);
      #pragma unroll
      for (int h=0;h<10;++h) qh_acc[h] += __shfl_xor(qh_acc[h], m, 64);
    }
    if (part == 0){
      s_qb[row] = qb_acc;
      #pragma unroll
      for (int h=0;h<10;++h) s_qh[row][h] = qh_acc[h];
    }
  }
  for (int k = tid; k < NT_*64; k += 256)
    s_hk[k] = (k < S1_) ? heights[b*S_TOT + S0_ + k] : 0;
  for (int idx = tid; idx < 16*NT_; idx += 256){
    int qq = idx / NT_, tt = idx - qq*NT_;
    int qr = q0 + qq; if (qr > S0_-1) qr = S0_-1;
    s_mb[qq][tt] = maskb[((size_t)(b*S0_ + qr))*NT_ + tt];
  }
  __syncthreads();

  const int qcol = lane & 15, khi = (lane>>4)<<2;
  int qme = q0 + qcol; if (qme > S0_-1) qme = S0_-1;
  const int hq = heights[b*S_TOT + qme];
  const float qb = s_qb[qcol];

  short8v qgf[4];
  #pragma unroll
  for (int kt=0; kt<4; ++kt) qgf[kt] = load_afrag(&s_qg[qcol][0], kt, khi);

  // ---- phase 1: all of this wave's QK tiles + bias + mask + per-wave max
  f32x4 sc[5][4];
  float tmw = -1e30f;
  #pragma unroll
  for (int it=0; it<5; ++it){
    const int t = it*4 + wv;
    if (t < NT_){
      u64 mb = s_mb[qcol][t];
      #pragma unroll
      for (int st=0; st<4; ++st){
        f32x4 c = (f32x4){0.f,0.f,0.f,0.f};
        #pragma unroll
        for (int kt=0; kt<4; ++kt){
          short8v a = *reinterpret_cast<const short8v*>(
              ZkF + (((size_t)(b*KT16_ + t*4 + st)*4 + kt)*64 + lane)*8);
          c = __builtin_amdgcn_mfma_f32_16x16x32_bf16(a, qgf[kt], c, 0,0,0);
        }
        int4 hk4 = *reinterpret_cast<const int4*>(&s_hk[t*64 + st*16 + khi]);
        #pragma unroll
        for (int r=0;r<4;++r){
          int hk = (&hk4.x)[r];
          int idx = min(max(hk - hq, 1), 10) - 1;
          float v = (c[r] + qb + s_qh[qcol][idx]) * SCALE_INV;
          int kl = st*16 + khi + r;
          v = ((mb >> kl) & 1ull) ? v : -9999.f;
          c[r] = v;
          tmw = fmaxf(tmw, v);
        }
        sc[it][st] = c;
      }
    }
  }
  tmw = fmaxf(tmw, __shfl_xor(tmw, 16, 64));
  tmw = fmaxf(tmw, __shfl_xor(tmw, 32, 64));
  if (lane < 16) s_mx[wv][lane] = tmw;
  __syncthreads();

  // ---- phase 2: global max (exact), exp, pack all P tiles to LDS
  const float m = fmaxf(fmaxf(s_mx[0][qcol], s_mx[1][qcol]),
                        fmaxf(s_mx[2][qcol], s_mx[3][qcol]));
  float ls = 0.f;
  #pragma unroll
  for (int it=0; it<5; ++it){
    const int t = it*4 + wv;
    if (t < NT_){
      #pragma unroll
      for (int st=0; st<4; ++st)
        #pragma unroll
        for (int r=0;r<4;++r){
          float p = __expf(sc[it][st][r] - m);
          ls += p;
          sc[it][st][r] = p;
        }
      short8v pa0, pa1;
      #pragma unroll
      for (int j=0;j<8;++j){
        pa0[j] = f2bf(sc[it][(j>>2)][j&3]);
        pa1[j] = f2bf(sc[it][2 + (j>>2)][j&3]);
      }
      s_pl[t][lane] = pa0;
      s_ph[t][lane] = pa1;
    }
  }
  ls += __shfl_xor(ls, 16, 64);
  ls += __shfl_xor(ls, 32, 64);
  if (lane < 16) s_sm[wv][lane] = ls;
  __syncthreads();

  // ---- phase 3: one uninterrupted PV stream over all 17 tiles
  float lrow[4];
  #pragma unroll
  for (int r=0;r<4;++r){
    int qr = khi + r;
    lrow[r] = s_sm[0][qr] + s_sm[1][qr] + s_sm[2][qr] + s_sm[3][qr];
  }
  f32x4 O[8];
  #pragma unroll
  for (int vt=0; vt<8; ++vt) O[vt] = (f32x4){0.f,0.f,0.f,0.f};
  for (int t=0; t<NT_; ++t){
    short8v pa0 = s_pl[t][lane];
    short8v pa1 = s_ph[t][lane];
    #pragma unroll
    for (int vt=0; vt<8; ++vt){
      size_t vb = ((size_t)b*32 + wv*8 + vt)*(2*NT_) + 2*t;
      short8v b0 = *reinterpret_cast<const short8v*>(VtF + (vb*64 + lane)*8);
      short8v b1 = *reinterpret_cast<const short8v*>(VtF + ((vb+1)*64 + lane)*8);
      O[vt] = __builtin_amdgcn_mfma_f32_16x16x32_bf16(pa0, b0, O[vt], 0,0,0);
      O[vt] = __builtin_amdgcn_mfma_f32_16x16x32_bf16(pa1, b1, O[vt], 0,0,0);
    }
  }
  __syncthreads();   // P buffers die; sUV/sO region born

  // ---- U = silu(x @ W_U + b) for own v-slice; uv = U * O / l -> sUV (bf16)
  f32x4 accu[8];
  #pragma unroll
  for (int vt=0; vt<8; ++vt) accu[vt] = (f32x4){0.f,0.f,0.f,0.f};
  {
    const short* xrow = &sX[qcol*XPAD];
    #pragma unroll
    for (int kt=0; kt<8; ++kt){
      short8v a = load_afrag(xrow, kt, khi);
      #pragma unroll
      for (int vt=0; vt<8; ++vt){
        int nt = wv*8 + vt;
        short8v bw = *reinterpret_cast<const short8v*>(WpU + ((size_t)(nt*8 + kt)*64 + lane)*8);
        accu[vt] = __builtin_amdgcn_mfma_f32_16x16x32_bf16(a, bw, accu[vt], 0,0,0);
      }
    }
  }
  float inv[4];
  #pragma unroll
  for (int r=0;r<4;++r) inv[r] = 1.f / lrow[r];
  #pragma unroll
  for (int vt=0; vt<8; ++vt){
    int v = wv*128 + vt*16 + qcol;
    float bu = b_U[v];
    #pragma unroll
    for (int r=0;r<4;++r){
      float u = silu_f(accu[vt][r] + bu);
      sUV[(khi + r)*UPAD + v] = f2bf(u * O[vt][r] * inv[r]);
    }
  }
  __syncthreads();

  // ---- out-proj: o = UV @ W_out + b (each wave: 4 n-tiles, K=512)
  f32x4 acc_o[4];
  #pragma unroll
  for (int j=0;j<4;++j) acc_o[j] = (f32x4){0.f,0.f,0.f,0.f};
  {
    const short* arow = &sUV[qcol*UPAD];
    #pragma unroll
    for (int kt=0; kt<16; ++kt){
      short8v a = load_afrag(arow, kt, khi);
      #pragma unroll
      for (int j=0;j<4;++j){
        int nt = wv*4 + j;
        short8v bw = *reinterpret_cast<const short8v*>(Wpo + ((size_t)(nt*16 + kt)*64 + lane)*8);
        acc_o[j] = __builtin_amdgcn_mfma_f32_16x16x32_bf16(a, bw, acc_o[j], 0,0,0);
      }
    }
  }
  #pragma unroll
  for (int j=0;j<4;++j){
    int col = (wv*4+j)*16 + qcol;
    float bv = b_out[col];
    #pragma unroll
    for (int r=0;r<4;++r){
      acc_o[j][r] += bv;
      sO[(khi + r)*XPAD + col] = f2bf(acc_o[j][r]);
    }
  }
  __syncthreads();

  // ---- gate = sigmoid([o, res] @ W_gate + b); final mix + write
  f32x4 acc_g[4];
  #pragma unroll
  for (int j=0;j<4;++j) acc_g[j] = (f32x4){0.f,0.f,0.f,0.f};
  {
    const short* orow_p = &sO[qcol*XPAD];
    const short* rrow_p = &sR[qcol*XPAD];
    #pragma unroll
    for (int kt=0; kt<8; ++kt){
      short8v a = load_afrag(orow_p, kt, khi);
      #pragma unroll
      for (int j=0;j<4;++j){
        int nt = wv*4 + j;
        short8v bw = *reinterpret_cast<const short8v*>(Wpg + ((size_t)(nt*16 + kt)*64 + lane)*8);
        acc_g[j] = __builtin_amdgcn_mfma_f32_16x16x32_bf16(a, bw, acc_g[j], 0,0,0);
      }
    }
    #pragma unroll
    for (int kt=0; kt<8; ++kt){
      short8v a = load_afrag(rrow_p, kt, khi);
      #pragma unroll
      for (int j=0;j<4;++j){
        int nt = wv*4 + j;
        short8v bw = *reinterpret_cast<const short8v*>(Wpg + ((size_t)(nt*16 + 8 + kt)*64 + lane)*8);
        acc_g[j] = __builtin_amdgcn_mfma_f32_16x16x32_bf16(a, bw, acc_g[j], 0,0,0);
      }
    }
  }
  #pragma unroll
  for (int j=0;j<4;++j){
    int col = (wv*4+j)*16 + qcol;
    float bg = b_gate[col];
    #pragma unroll
    for (int r=0;r<4;++r){
      int q = q0 + khi + r;
      if (q < S0_){
        float res = seq[((size_t)(b*S_TOT + q))*D_ + col];
        float g = 1.f/(1.f + __expf(-(acc_g[j][r] + bg)));
        out[((size_t)(b*S_TOT + q))*D_ + col] = g*acc_o[j][r] + (1.f-g)*res;
      }
    }
  }
}

extern "C" void kernel_launch(void* const* d_in, const int* in_sizes, int n_in,
                              void* d_out, int out_size, void* d_ws, size_t ws_size,
                              hipStream_t stream)
{
  const float* seq    = (const float*)d_in[0];
  const unsigned char* amask = (const unsigned char*)d_in[1];
  const int*   heights= (const int*)d_in[2];
  const float* W_init = (const float*)d_in[3];
  const float* b_init = (const float*)d_in[4];
  const float* ln_g   = (const float*)d_in[5];
  const float* ln_b   = (const float*)d_in[6];
  const float* W_U    = (const float*)d_in[7];
  const float* b_U    = (const float*)d_in[8];
  const float* W_V    = (const float*)d_in[9];
  const float* b_V    = (const float*)d_in[10];
  const float* W_Z    = (const float*)d_in[11];
  const float* b_Z    = (const float*)d_in[12];
  const float* os_g   = (const float*)d_in[13];
  const float* os_b   = (const float*)d_in[14];
  const float* embH   = (const float*)d_in[15];
  const float* W_out  = (const float*)d_in[16];
  const float* b_out  = (const float*)d_in[17];
  const float* W_gate = (const float*)d_in[18];
  const float* b_gate = (const float*)d_in[19];
  float* out = (float*)d_out;

  char* w = (char*)d_ws;
  short* Zb  = (short*)w;                w += (size_t)16512*128*2;         // bf16 Z row-major
  short* VtF = (short*)w;                w += (size_t)8*32*(2*NT_)*64*8*2; // V B-frags
  short* ZkF = (short*)w;                w += (size_t)NB_*KT16_*4*64*8*2;  // Z-key A-frags
  short* xb  = (short*)w;                w += (size_t)16384*256*2;
  u64*  maskb = (u64*)w;                 w += (size_t)NB_*S0_*NT_*8;
  short* WpI = (short*)w;                w += (size_t)65536*2;
  short* WpU = (short*)w;                w += (size_t)131072*2;
  short* WpV = (short*)w;                w += (size_t)131072*2;
  short* WpZ = (short*)w;                w += (size_t)32768*2;
  short* WpO = (short*)w;                w += (size_t)131072*2;
  short* WpG = (short*)w;                w += (size_t)131072*2;

  hipLaunchKernelGGL(k_prep, dim3(304 + (NB_*S0_*NT_ + 3)/4), dim3(256), 0, stream,
      W_init, W_U, W_V, W_Z, W_out, W_gate,
      WpI, WpU, WpV, WpZ, WpO, WpG, amask, maskb);

  hipLaunchKernelGGL(k_x, dim3(256), dim3(256), 0, stream,
      seq, WpI, b_init, ln_g, ln_b, xb, out);

  hipLaunchKernelGGL(k_gemmZ, dim3(256, 2), dim3(256), 0, stream,
      xb, WpZ, b_Z, Zb);
  hipLaunchKernelGGL(k_packZ, dim3((NB_*KT16_*4 + 3)/4), dim3(256), 0, stream, Zb, ZkF);
  hipLaunchKernelGGL(k_gemmV, dim3(17, 8, 8), dim3(256), 0, stream,
      xb, WpV, b_V, VtF);

  hipLaunchKernelGGL(k_flash, dim3(512), dim3(256), 0, stream,
      Zb, ZkF, VtF, maskb, xb, WpU, b_U, WpO, b_out, WpG, b_gate,
      seq, out, heights, os_g, os_b, embH);
}